// Round 2
// baseline (2998.408 us; speedup 1.0000x reference)
//
#include <hip/hip_runtime.h>

typedef float f32x4 __attribute__((ext_vector_type(4)));
typedef __bf16 bf16x8 __attribute__((ext_vector_type(8)));
typedef unsigned int u32x4 __attribute__((ext_vector_type(4)));
typedef unsigned short u16x8 __attribute__((ext_vector_type(8)));

#define DI __device__ __forceinline__

constexpr int B_ = 4, T_ = 2048, C_ = 2048, H_ = 32;
constexpr int M_ = B_ * T_;  // 8192 rows

DI unsigned short f2bf(float f) {
  unsigned u = __float_as_uint(f);
  return (unsigned short)((u + 0x7FFFu + ((u >> 16) & 1u)) >> 16);
}
DI float bf2f(unsigned short h) { return __uint_as_float(((unsigned)h) << 16); }

DI void gl16(const void* g, void* l) {
  __builtin_amdgcn_global_load_lds(
      (__attribute__((address_space(1))) const unsigned int*)g,
      (__attribute__((address_space(3))) unsigned int*)l, 16, 0, 0);
}
DI void gl4(const void* g, void* l) {
  __builtin_amdgcn_global_load_lds(
      (__attribute__((address_space(1))) const unsigned int*)g,
      (__attribute__((address_space(3))) unsigned int*)l, 4, 0, 0);
}

// quad (4-lane) sum via DPP: all 4 lanes of each quad end with the quad total
DI float qsum(float x) {
  int t = __builtin_amdgcn_update_dpp(0, __float_as_int(x), 0xB1, 0xF, 0xF, true);
  x += __int_as_float(t);
  t = __builtin_amdgcn_update_dpp(0, __float_as_int(x), 0x4E, 0xF, 0xF, true);
  return x + __int_as_float(t);
}

// ---------------- transpose f32 (R x C) -> bf16 (C x R) ----------------
__global__ __launch_bounds__(256) void k_transpose(const float* __restrict__ in,
                                                   unsigned short* __restrict__ out,
                                                   int R, int C) {
  __shared__ float tile[32][33];
  int c0 = blockIdx.x * 32, r0 = blockIdx.y * 32;
  int tx = threadIdx.x & 31, ty = threadIdx.x >> 5;
#pragma unroll
  for (int i = 0; i < 4; ++i) {
    int r = r0 + ty * 4 + i, c = c0 + tx;
    if (r < R && c < C) tile[ty * 4 + i][tx] = in[(size_t)r * C + c];
  }
  __syncthreads();
#pragma unroll
  for (int i = 0; i < 4; ++i) {
    int c = c0 + ty * 4 + i, r = r0 + tx;
    if (r < R && c < C) out[(size_t)c * R + r] = f2bf(tile[tx][ty * 4 + i]);
  }
}

// fused token-shift mix staging: compute bf16 mix tile into As (linear chunk layout)
DI void stage_mix(const float* __restrict__ x, const float* __restrict__ xprev,
                  const float* __restrict__ coef, unsigned short* As,
                  int m0, int kt, int wv, int lane) {
  const int lr = lane >> 3, lc = (lane & 7) * 8;
  f32x4 c0 = *(const f32x4*)(coef + kt + lc);
  f32x4 c1 = *(const f32x4*)(coef + kt + lc + 4);
#pragma unroll
  for (int i = 0; i < 4; ++i) {
    int chunk = wv * 4 + i;
    int r = chunk * 8 + lr;
    int m = m0 + r;
    const float* xp = x + (size_t)m * C_ + kt + lc;
    const float* pp = (m & (T_ - 1)) ? (xp - C_)
                                     : (xprev + (size_t)(m >> 11) * C_ + kt + lc);
    f32x4 xv0 = *(const f32x4*)xp, xv1 = *(const f32x4*)(xp + 4);
    f32x4 pv0 = *(const f32x4*)pp, pv1 = *(const f32x4*)(pp + 4);
    unsigned short u[8];
#pragma unroll
    for (int j = 0; j < 4; ++j) u[j] = f2bf(xv0[j] + (pv0[j] - xv0[j]) * c0[j]);
#pragma unroll
    for (int j = 0; j < 4; ++j) u[4 + j] = f2bf(xv1[j] + (pv1[j] - xv1[j]) * c1[j]);
    u32x4 pk;
#pragma unroll
    for (int j = 0; j < 4; ++j) pk[j] = (unsigned)u[2 * j] | ((unsigned)u[2 * j + 1] << 16);
    *(u32x4*)((char*)As + chunk * 1024 + lane * 16) = pk;
  }
}

// ---------------- big GEMM: 128x128 tile, K=2048, A = fused mix or plain bf16 ----
// EPI 0: RB = bf16(acc)
// EPI 1: VB = bf16(acc + (vfirst - acc)*svb)
// EPI 2: kk-norm fused: KB, AHB, BHB
// EPI 3: f32 store (final output GEMM)
template <int EPI, bool FUSED>
__global__ __launch_bounds__(256, 2) void k_gemm_big(
    const unsigned short* __restrict__ A,
    const float* __restrict__ x, const float* __restrict__ xprev,
    const float* __restrict__ coef,
    const unsigned short* __restrict__ Bt,
    float* __restrict__ outF, unsigned short* __restrict__ outB,
    const unsigned short* __restrict__ svb, const float* __restrict__ vfirst,
    const unsigned short* __restrict__ abf,
    const float* __restrict__ k_k, const float* __restrict__ k_a,
    unsigned short* __restrict__ ahb, unsigned short* __restrict__ bhb) {
  __shared__ __align__(16) unsigned short As[128][64];
  __shared__ __align__(16) unsigned short Bs[128][64];
  const int tid = threadIdx.x, lane = tid & 63, wv = tid >> 6;
  const int m0 = blockIdx.y * 128, n0 = blockIdx.x * 128;
  const int wm = (wv >> 1) * 64, wn = (wv & 1) * 64;
  const int lr = lane >> 3, lc = (lane & 7) * 8;
  f32x4 acc[4][4] = {};
  for (int kt = 0; kt < C_; kt += 64) {
    __syncthreads();
    if constexpr (FUSED) {
      stage_mix(x, xprev, coef, &As[0][0], m0, kt, wv, lane);
#pragma unroll
      for (int i = 0; i < 4; ++i) {
        int chunk = wv * 4 + i, r = chunk * 8 + lr;
        gl16(Bt + (size_t)(n0 + r) * C_ + kt + lc, (char*)&Bs[0][0] + chunk * 1024);
      }
    } else {
#pragma unroll
      for (int i = 0; i < 4; ++i) {
        int chunk = wv * 4 + i, r = chunk * 8 + lr;
        gl16(A + (size_t)(m0 + r) * C_ + kt + lc, (char*)&As[0][0] + chunk * 1024);
        gl16(Bt + (size_t)(n0 + r) * C_ + kt + lc, (char*)&Bs[0][0] + chunk * 1024);
      }
    }
    __syncthreads();
    const int rr = lane & 15;
#pragma unroll
    for (int kh = 0; kh < 2; ++kh) {
      const int kof = kh * 32 + (lane >> 4) * 8;
      bf16x8 af[4], bfv[4];
#pragma unroll
      for (int i = 0; i < 4; ++i) af[i] = *(const bf16x8*)&As[wm + i * 16 + rr][kof];
#pragma unroll
      for (int j = 0; j < 4; ++j) bfv[j] = *(const bf16x8*)&Bs[wn + j * 16 + rr][kof];
#pragma unroll
      for (int i = 0; i < 4; ++i)
#pragma unroll
        for (int j = 0; j < 4; ++j)
          acc[i][j] = __builtin_amdgcn_mfma_f32_16x16x32_bf16(af[i], bfv[j], acc[i][j], 0, 0, 0);
    }
  }
  const int cr = (lane >> 4) * 4, cc2 = lane & 15;
  if constexpr (EPI == 2) {
    float kkv[4], kav[4];
#pragma unroll
    for (int j = 0; j < 4; ++j) {
      int col = n0 + wn + j * 16 + cc2;
      kkv[j] = k_k[col];
      kav[j] = k_a[col];
    }
#pragma unroll
    for (int i = 0; i < 4; ++i)
#pragma unroll
      for (int q = 0; q < 4; ++q) {
        int row = m0 + wm + i * 16 + cr + q;
        float kk4[4], p = 0.f;
#pragma unroll
        for (int j = 0; j < 4; ++j) {
          float kkc = acc[i][j][q] * kkv[j];
          kk4[j] = kkc;
          p += kkc * kkc;
        }
        p += __shfl_xor(p, 1); p += __shfl_xor(p, 2);
        p += __shfl_xor(p, 4); p += __shfl_xor(p, 8);
        float inv = 1.f / fmaxf(sqrtf(p), 1e-12f);
#pragma unroll
        for (int j = 0; j < 4; ++j) {
          int col = n0 + wn + j * 16 + cc2;
          size_t off = (size_t)row * C_ + col;
          float kkn = kk4[j] * inv;
          float a = bf2f(abf[off]);
          ahb[off] = f2bf(-kkn);
          bhb[off] = f2bf(kkn * a);
          outB[off] = f2bf(acc[i][j][q] * (1.f + (a - 1.f) * kav[j]));
        }
      }
  } else {
#pragma unroll
    for (int i = 0; i < 4; ++i)
#pragma unroll
      for (int j = 0; j < 4; ++j)
#pragma unroll
        for (int q = 0; q < 4; ++q) {
          int row = m0 + wm + i * 16 + cr + q;
          int col = n0 + wn + j * 16 + cc2;
          size_t off = (size_t)row * C_ + col;
          float v = acc[i][j][q];
          if constexpr (EPI == 0) {
            outB[off] = f2bf(v);
          } else if constexpr (EPI == 1) {
            float s = bf2f(svb[off]);
            outB[off] = f2bf(v + (vfirst[off] - v) * s);
          } else {
            outF[off] = v;
          }
        }
  }
}

// ---------------- down GEMM: H(bf16, MxN) = act(mix(x) @ Bt^T), N in {32,64,128} --
// ACT: 0 none, 1 tanh, 2 sigmoid
template <int N, int ACT>
__global__ __launch_bounds__(256, 2) void k_down(
    const float* __restrict__ x, const float* __restrict__ xprev,
    const float* __restrict__ coef, const unsigned short* __restrict__ Bt,
    unsigned short* __restrict__ out) {
  __shared__ __align__(16) unsigned short As[128][64];
  __shared__ __align__(16) unsigned short Bs[N][64];
  const int tid = threadIdx.x, lane = tid & 63, wv = tid >> 6;
  const int m0 = blockIdx.x * 128;
  const int wm = wv * 32;
  const int lr = lane >> 3, lc = (lane & 7) * 8;
  f32x4 acc[2][N / 16] = {};
  for (int kt = 0; kt < C_; kt += 64) {
    __syncthreads();
    stage_mix(x, xprev, coef, &As[0][0], m0, kt, wv, lane);
#pragma unroll
    for (int i = 0; i < N / 32; ++i) {
      int chunk = wv * (N / 32) + i, r = chunk * 8 + lr;
      gl16(Bt + (size_t)r * C_ + kt + lc, (char*)&Bs[0][0] + chunk * 1024);
    }
    __syncthreads();
    const int rr = lane & 15;
#pragma unroll
    for (int kh = 0; kh < 2; ++kh) {
      const int kof = kh * 32 + (lane >> 4) * 8;
      bf16x8 af[2], bfv[N / 16];
#pragma unroll
      for (int i = 0; i < 2; ++i) af[i] = *(const bf16x8*)&As[wm + i * 16 + rr][kof];
#pragma unroll
      for (int j = 0; j < N / 16; ++j) bfv[j] = *(const bf16x8*)&Bs[j * 16 + rr][kof];
#pragma unroll
      for (int i = 0; i < 2; ++i)
#pragma unroll
        for (int j = 0; j < N / 16; ++j)
          acc[i][j] = __builtin_amdgcn_mfma_f32_16x16x32_bf16(af[i], bfv[j], acc[i][j], 0, 0, 0);
    }
  }
  const int cr = (lane >> 4) * 4, cc2 = lane & 15;
#pragma unroll
  for (int i = 0; i < 2; ++i)
#pragma unroll
    for (int j = 0; j < N / 16; ++j)
#pragma unroll
      for (int q = 0; q < 4; ++q) {
        int row = m0 + wm + i * 16 + cr + q;
        int col = j * 16 + cc2;
        float v = acc[i][j][q];
        if (ACT == 1) v = tanhf(v);
        else if (ACT == 2) v = 1.f / (1.f + expf(-v));
        out[(size_t)row * N + col] = f2bf(v);
      }
}

// ---------------- up GEMM (K in {32,64,128}), single K pass ----------------
// MODE 0: wd = exp(-exp(-softplus(-(bias+up)) - 0.5)) -> outF (f32)
// MODE 1: sigmoid(bias+up) -> outB (bf16)
// MODE 3: up -> outB (bf16)
template <int K, int MODE>
__global__ __launch_bounds__(256, 2) void k_up(
    const unsigned short* __restrict__ A, const unsigned short* __restrict__ Bt,
    const float* __restrict__ bias, float* __restrict__ outF,
    unsigned short* __restrict__ outB) {
  __shared__ __align__(16) unsigned short As[128][K];
  __shared__ __align__(16) unsigned short Bs[128][K];
  const int tid = threadIdx.x, lane = tid & 63, wv = tid >> 6;
  const int m0 = blockIdx.y * 128, n0 = blockIdx.x * 128;
  const int wm = (wv >> 1) * 64, wn = (wv & 1) * 64;
  constexpr int LPR = K / 8;
  constexpr int RPC = 64 / LPR;
  const int lr = lane / LPR, lc = (lane % LPR) * 8;
  f32x4 acc[4][4] = {};
#pragma unroll
  for (int i = 0; i < K / 16; ++i) {
    int chunk = wv * (K / 16) + i;
    int r = chunk * RPC + lr;
    gl16(A + (size_t)(m0 + r) * K + lc, (char*)&As[0][0] + chunk * 1024);
    gl16(Bt + (size_t)(n0 + r) * K + lc, (char*)&Bs[0][0] + chunk * 1024);
  }
  __syncthreads();
  const int rr = lane & 15;
#pragma unroll
  for (int ks = 0; ks < K / 32; ++ks) {
    const int kof = ks * 32 + (lane >> 4) * 8;
    bf16x8 af[4], bfv[4];
#pragma unroll
    for (int i = 0; i < 4; ++i) af[i] = *(const bf16x8*)&As[wm + i * 16 + rr][kof];
#pragma unroll
    for (int j = 0; j < 4; ++j) bfv[j] = *(const bf16x8*)&Bs[wn + j * 16 + rr][kof];
#pragma unroll
    for (int i = 0; i < 4; ++i)
#pragma unroll
      for (int j = 0; j < 4; ++j)
        acc[i][j] = __builtin_amdgcn_mfma_f32_16x16x32_bf16(af[i], bfv[j], acc[i][j], 0, 0, 0);
  }
  const int cr = (lane >> 4) * 4, cc2 = lane & 15;
#pragma unroll
  for (int i = 0; i < 4; ++i)
#pragma unroll
    for (int j = 0; j < 4; ++j)
#pragma unroll
      for (int q = 0; q < 4; ++q) {
        int row = m0 + wm + i * 16 + cr + q;
        int col = n0 + wn + j * 16 + cc2;
        size_t off = (size_t)row * C_ + col;
        float up = acc[i][j][q];
        if (MODE == 0) {
          float z = -(bias[col] + up);
          float sp = fmaxf(z, 0.f) + log1pf(expf(-fabsf(z)));
          outF[off] = expf(-expf(-sp - 0.5f));
        } else if (MODE == 1) {
          outB[off] = f2bf(1.f / (1.f + expf(-(bias[col] + up))));
        } else {
          outB[off] = f2bf(up);
        }
      }
}

// ---------------- WKV recurrent scan (bf16 streams, f32 wd, fused bonus) -------
// 1 block (4 waves) per (b,h). Lane owns S[iRow][cg*16..+15]. LDS slot layout:
// [r 128B | a 128B | k 128B | b 128B | v 128B | wd 256B] = 896B, NBUF=5.
__global__ __launch_bounds__(256) void k_scan(
    const unsigned short* __restrict__ RB, const float* __restrict__ WD,
    const unsigned short* __restrict__ KB, const unsigned short* __restrict__ VB,
    const unsigned short* __restrict__ AHB, const unsigned short* __restrict__ BHB,
    const float* __restrict__ s0, const float* __restrict__ r_k,
    float* __restrict__ out, float* __restrict__ bscal) {
  __shared__ __align__(16) char sv[5 * 896];
  const int tid = threadIdx.x, lane = tid & 63, wid = tid >> 6;
  const int bh = blockIdx.x, b = bh >> 5, h = bh & 31;
  const int cg = lane & 3, iRow = (wid << 4) + (lane >> 2);
  float S[16];
  {
    const float* sp = s0 + ((size_t)(b * H_ + h) * 64 + iRow) * 64 + cg * 16;
#pragma unroll
    for (int j = 0; j < 16; ++j) S[j] = sp[j];
  }
  float rk[16];
#pragma unroll
  for (int j = 0; j < 16; ++j) rk[j] = r_k[h * 64 + cg * 16 + j];
  const size_t rowB0 = (size_t)b * T_ * C_ + h * 64;
  auto issue = [&](int t, int slot) {
    int tt = t < T_ ? t : T_ - 1;
    size_t e = rowB0 + (size_t)tt * C_;
    char* base = sv + slot * 896;
    if (wid == 0) {
      const char* g = lane < 32 ? (const char*)(RB + e) + lane * 4
                                : (const char*)(AHB + e) + (lane - 32) * 4;
      gl4(g, base);
    } else if (wid == 1) {
      const char* g = lane < 32 ? (const char*)(KB + e) + lane * 4
                                : (const char*)(BHB + e) + (lane - 32) * 4;
      gl4(g, base + 256);
    } else if (wid == 2) {
      gl4((const char*)(WD + e) + lane * 4, base + 640);
    } else {
      if (lane < 32) gl4((const char*)(VB + e) + lane * 4, base + 512);
    }
  };
  issue(0, 0); issue(1, 1); issue(2, 2);
  int slot = 0, slot3 = 3;
  for (int t = 0; t < T_; ++t) {
    issue(t + 3, slot3);
    asm volatile("s_waitcnt vmcnt(3)" ::: "memory");
    __builtin_amdgcn_s_barrier();
    asm volatile("" ::: "memory");
    const char* bp = sv + slot * 896;
    float rr[16], aa[16], kk[16], bb[16], ww[16];
    {
      const u16x8* p0 = (const u16x8*)(bp + 0 + cg * 32);
      const u16x8* p1 = (const u16x8*)(bp + 128 + cg * 32);
      const u16x8* p2 = (const u16x8*)(bp + 256 + cg * 32);
      const u16x8* p3 = (const u16x8*)(bp + 384 + cg * 32);
      u16x8 q0 = p0[0], q1 = p0[1], q2 = p1[0], q3 = p1[1];
      u16x8 q4 = p2[0], q5 = p2[1], q6 = p3[0], q7 = p3[1];
#pragma unroll
      for (int j = 0; j < 8; ++j) {
        rr[j] = bf2f(q0[j]); rr[8 + j] = bf2f(q1[j]);
        aa[j] = bf2f(q2[j]); aa[8 + j] = bf2f(q3[j]);
        kk[j] = bf2f(q4[j]); kk[8 + j] = bf2f(q5[j]);
        bb[j] = bf2f(q6[j]); bb[8 + j] = bf2f(q7[j]);
      }
      const f32x4* wp = (const f32x4*)(bp + 640 + cg * 64);
#pragma unroll
      for (int q = 0; q < 4; ++q) {
        f32x4 wv4 = wp[q];
#pragma unroll
        for (int j = 0; j < 4; ++j) ww[q * 4 + j] = wv4[j];
      }
    }
    float vi = bf2f(*(const unsigned short*)(bp + 512 + iRow * 2));
    float sa = 0.f;
#pragma unroll
    for (int j = 0; j < 16; ++j) sa += S[j] * aa[j];
    sa = qsum(sa);
    float o = 0.f, bon = 0.f;
#pragma unroll
    for (int j = 0; j < 16; ++j) {
      float s2 = S[j] * ww[j] + sa * bb[j] + vi * kk[j];
      S[j] = s2;
      o += s2 * rr[j];
      bon += rr[j] * kk[j] * rk[j];
    }
    o = qsum(o);
    bon = qsum(bon);
    if (cg == 0) out[rowB0 + (size_t)t * C_ + iRow] = o;
    if (tid == 0) bscal[(size_t)(b * T_ + t) * H_ + h] = bon;
    asm volatile("" ::: "memory");
    slot = (slot + 1 == 5) ? 0 : slot + 1;
    slot3 = (slot3 + 1 == 5) ? 0 : slot3 + 1;
  }
}

// ---------------- GroupNorm + bonus + gate (wave per (b,t,h)) ----------------
__global__ __launch_bounds__(256) void k_gn(
    const float* __restrict__ o, const unsigned short* __restrict__ v,
    const unsigned short* __restrict__ g, const float* __restrict__ bscal,
    const float* __restrict__ lnw, const float* __restrict__ lnb,
    unsigned short* __restrict__ outg) {
  int wid = blockIdx.x * 4 + (threadIdx.x >> 6);
  int lane = threadIdx.x & 63;
  int h = wid & (H_ - 1);
  size_t bt = (size_t)(wid >> 5);
  size_t off = bt * C_ + h * 64 + lane;
  int c = h * 64 + lane;
  float x = o[off];
  float mu = x;
#pragma unroll
  for (int m = 1; m < 64; m <<= 1) mu += __shfl_xor(mu, m);
  mu *= (1.f / 64.f);
  float d = x - mu;
  float var = d * d;
#pragma unroll
  for (int m = 1; m < 64; m <<= 1) var += __shfl_xor(var, m);
  var *= (1.f / 64.f);
  float y = d * rsqrtf(var + 6.4e-4f) * lnw[c] + lnb[c];
  float res = (y + bscal[bt * H_ + h] * bf2f(v[off])) * bf2f(g[off]);
  outg[off] = f2bf(res);
}

// ---------------- host launch ----------------
extern "C" void kernel_launch(void* const* d_in, const int* in_sizes, int n_in,
                              void* d_out, int out_size, void* d_ws, size_t ws_size,
                              hipStream_t stream) {
  const float* x      = (const float*)d_in[0];
  const float* vfirst = (const float*)d_in[1];
  const float* xprev  = (const float*)d_in[2];
  const float* wkv0   = (const float*)d_in[3];
  const float* x_r = (const float*)d_in[4];
  const float* x_w = (const float*)d_in[5];
  const float* x_k = (const float*)d_in[6];
  const float* x_v = (const float*)d_in[7];
  const float* x_a = (const float*)d_in[8];
  const float* x_g = (const float*)d_in[9];
  const float* w0 = (const float*)d_in[10];
  const float* w1 = (const float*)d_in[11];
  const float* w2 = (const float*)d_in[12];
  const float* a0 = (const float*)d_in[13];
  const float* a1 = (const float*)d_in[14];
  const float* a2 = (const float*)d_in[15];
  const float* v0 = (const float*)d_in[16];
  const float* v1 = (const float*)d_in[17];
  const float* v2 = (const float*)d_in[18];
  const float* g1 = (const float*)d_in[19];
  const float* g2 = (const float*)d_in[20];
  const float* k_k = (const float*)d_in[21];
  const float* k_a = (const float*)d_in[22];
  const float* r_k = (const float*)d_in[23];
  const float* Wr = (const float*)d_in[24];
  const float* Wk = (const float*)d_in[25];
  const float* Wv = (const float*)d_in[26];
  const float* Wo = (const float*)d_in[27];
  const float* lnw = (const float*)d_in[28];
  const float* lnb = (const float*)d_in[29];
  float* out = (float*)d_out;
  char* ws = (char*)d_ws;

  // ---- workspace layout: 251,396,096 B total (~239.8 MiB) ----
  size_t woff = 0;
  auto alloc = [&](size_t n) { char* p = ws + woff; woff += n; return p; };
  char* R1 = alloc(67108864);                       // ABF|SVB -> WD (f32)
  unsigned short* ABF = (unsigned short*)R1;
  unsigned short* SVB = (unsigned short*)(R1 + 33554432);
  float* WD = (float*)R1;
  unsigned short* WT  = (unsigned short*)alloc(8388608);   // transposed big weight
  unsigned short* W1T = (unsigned short*)alloc(262144);
  unsigned short* A1T = (unsigned short*)alloc(262144);
  unsigned short* V1T = (unsigned short*)alloc(131072);
  unsigned short* G1T = (unsigned short*)alloc(524288);
  unsigned short* W2T = (unsigned short*)alloc(262144);
  unsigned short* A2T = (unsigned short*)alloc(262144);
  unsigned short* V2T = (unsigned short*)alloc(131072);
  unsigned short* G2T = (unsigned short*)alloc(524288);
  unsigned short* HWB = (unsigned short*)alloc(1048576);
  unsigned short* HAB = (unsigned short*)alloc(1048576);
  unsigned short* HVB = (unsigned short*)alloc(524288);
  unsigned short* HGB = (unsigned short*)alloc(2097152);
  unsigned short* RB  = (unsigned short*)alloc(33554432);
  unsigned short* KB  = (unsigned short*)alloc(33554432);
  unsigned short* VB  = (unsigned short*)alloc(33554432);
  unsigned short* AHB = (unsigned short*)alloc(33554432);
  unsigned short* BHB = (unsigned short*)alloc(33554432);
  float* bscal = (float*)alloc(1048576);
  unsigned short* GBF  = AHB;  // post-scan overlay (AHB dead)
  unsigned short* OUTG = BHB;  // post-scan overlay (BHB dead)

  dim3 blk(256);
  dim3 gg(16, 64);

  // small weight transposes (K-contiguous layouts)
  k_transpose<<<dim3(2, 64), blk, 0, stream>>>(w1, W1T, 2048, 64);
  k_transpose<<<dim3(2, 64), blk, 0, stream>>>(a1, A1T, 2048, 64);
  k_transpose<<<dim3(1, 64), blk, 0, stream>>>(v1, V1T, 2048, 32);
  k_transpose<<<dim3(4, 64), blk, 0, stream>>>(g1, G1T, 2048, 128);
  k_transpose<<<dim3(64, 2), blk, 0, stream>>>(w2, W2T, 64, 2048);
  k_transpose<<<dim3(64, 2), blk, 0, stream>>>(a2, A2T, 64, 2048);
  k_transpose<<<dim3(64, 1), blk, 0, stream>>>(v2, V2T, 32, 2048);
  k_transpose<<<dim3(64, 4), blk, 0, stream>>>(g2, G2T, 128, 2048);

  // a-chain, v-chain (need ABF / SVB before K/V projections)
  k_down<64, 0><<<dim3(64), blk, 0, stream>>>(x, xprev, x_a, A1T, HAB);
  k_up<64, 1><<<gg, blk, 0, stream>>>(HAB, A2T, a0, nullptr, ABF);
  k_down<32, 0><<<dim3(64), blk, 0, stream>>>(x, xprev, x_v, V1T, HVB);
  k_up<32, 1><<<gg, blk, 0, stream>>>(HVB, V2T, v0, nullptr, SVB);

  // projections (WT slot reused; fused-mix A staging)
  k_transpose<<<dim3(64, 64), blk, 0, stream>>>(Wr, WT, 2048, 2048);
  k_gemm_big<0, true><<<gg, blk, 0, stream>>>(nullptr, x, xprev, x_r, WT,
      nullptr, RB, nullptr, nullptr, nullptr, nullptr, nullptr, nullptr, nullptr);
  k_transpose<<<dim3(64, 64), blk, 0, stream>>>(Wv, WT, 2048, 2048);
  k_gemm_big<1, true><<<gg, blk, 0, stream>>>(nullptr, x, xprev, x_v, WT,
      nullptr, VB, SVB, vfirst, nullptr, nullptr, nullptr, nullptr, nullptr);
  k_transpose<<<dim3(64, 64), blk, 0, stream>>>(Wk, WT, 2048, 2048);
  k_gemm_big<2, true><<<gg, blk, 0, stream>>>(nullptr, x, xprev, x_k, WT,
      nullptr, KB, nullptr, nullptr, ABF, k_k, k_a, AHB, BHB);

  // w-chain (ABF/SVB dead -> WD overlays them)
  k_down<64, 1><<<dim3(64), blk, 0, stream>>>(x, xprev, x_w, W1T, HWB);
  k_up<64, 0><<<gg, blk, 0, stream>>>(HWB, W2T, w0, WD, nullptr);

  // recurrent scan (writes scan-out to d_out + per-(t,h) bonus scalars)
  k_scan<<<dim3(128), blk, 0, stream>>>(RB, WD, KB, VB, AHB, BHB, wkv0, r_k, out, bscal);

  // g-chain (post-scan; GBF overlays AHB)
  k_down<128, 2><<<dim3(64), blk, 0, stream>>>(x, xprev, x_g, G1T, HGB);
  k_up<128, 3><<<gg, blk, 0, stream>>>(HGB, G2T, nullptr, nullptr, GBF);

  // GroupNorm + bonus + gate (OUTG overlays BHB)
  k_gn<<<dim3(65536), blk, 0, stream>>>(out, VB, GBF, bscal, lnw, lnb, OUTG);

  // final projection
  k_transpose<<<dim3(64, 64), blk, 0, stream>>>(Wo, WT, 2048, 2048);
  k_gemm_big<3, false><<<gg, blk, 0, stream>>>(OUTG, nullptr, nullptr, nullptr, WT,
      out, nullptr, nullptr, nullptr, nullptr, nullptr, nullptr, nullptr, nullptr);
}

// Round 3
// 2153.211 us; speedup vs baseline: 1.3925x; 1.3925x over previous
//
#include <hip/hip_runtime.h>

typedef float f32x4 __attribute__((ext_vector_type(4)));
typedef __bf16 bf16x8 __attribute__((ext_vector_type(8)));
typedef unsigned int u32x4 __attribute__((ext_vector_type(4)));

#define DI __device__ __forceinline__

constexpr int B_ = 4, T_ = 2048, C_ = 2048, H_ = 32;
constexpr int M_ = B_ * T_;  // 8192 rows

DI unsigned short f2bf(float f) {
  unsigned u = __float_as_uint(f);
  return (unsigned short)((u + 0x7FFFu + ((u >> 16) & 1u)) >> 16);
}
DI float bf2f(unsigned short h) { return __uint_as_float(((unsigned)h) << 16); }

DI void gl16(const void* g, void* l) {
  __builtin_amdgcn_global_load_lds(
      (__attribute__((address_space(1))) const unsigned int*)g,
      (__attribute__((address_space(3))) unsigned int*)l, 16, 0, 0);
}

// quad (4-lane) sum via DPP: all 4 lanes of each quad end with the quad total
DI float qsum(float x) {
  int t = __builtin_amdgcn_update_dpp(0, __float_as_int(x), 0xB1, 0xF, 0xF, true);
  x += __int_as_float(t);
  t = __builtin_amdgcn_update_dpp(0, __float_as_int(x), 0x4E, 0xF, 0xF, true);
  return x + __int_as_float(t);
}

// ---------------- transpose f32 (R x C) -> bf16 (C x R) ----------------
__global__ __launch_bounds__(256) void k_transpose(const float* __restrict__ in,
                                                   unsigned short* __restrict__ out,
                                                   int R, int C) {
  __shared__ float tile[32][33];
  int c0 = blockIdx.x * 32, r0 = blockIdx.y * 32;
  int tx = threadIdx.x & 31, ty = threadIdx.x >> 5;
#pragma unroll
  for (int i = 0; i < 4; ++i) {
    int r = r0 + ty * 4 + i, c = c0 + tx;
    if (r < R && c < C) tile[ty * 4 + i][tx] = in[(size_t)r * C + c];
  }
  __syncthreads();
#pragma unroll
  for (int i = 0; i < 4; ++i) {
    int c = c0 + ty * 4 + i, r = r0 + tx;
    if (r < R && c < C) out[(size_t)c * R + r] = f2bf(tile[tx][ty * 4 + i]);
  }
}

// fused token-shift mix staging: compute bf16 mix tile into As (linear chunk layout)
DI void stage_mix(const float* __restrict__ x, const float* __restrict__ xprev,
                  const float* __restrict__ coef, unsigned short* As,
                  int m0, int kt, int wv, int lane) {
  const int lr = lane >> 3, lc = (lane & 7) * 8;
  f32x4 c0 = *(const f32x4*)(coef + kt + lc);
  f32x4 c1 = *(const f32x4*)(coef + kt + lc + 4);
#pragma unroll
  for (int i = 0; i < 4; ++i) {
    int chunk = wv * 4 + i;
    int r = chunk * 8 + lr;
    int m = m0 + r;
    const float* xp = x + (size_t)m * C_ + kt + lc;
    const float* pp = (m & (T_ - 1)) ? (xp - C_)
                                     : (xprev + (size_t)(m >> 11) * C_ + kt + lc);
    f32x4 xv0 = *(const f32x4*)xp, xv1 = *(const f32x4*)(xp + 4);
    f32x4 pv0 = *(const f32x4*)pp, pv1 = *(const f32x4*)(pp + 4);
    unsigned short u[8];
#pragma unroll
    for (int j = 0; j < 4; ++j) u[j] = f2bf(xv0[j] + (pv0[j] - xv0[j]) * c0[j]);
#pragma unroll
    for (int j = 0; j < 4; ++j) u[4 + j] = f2bf(xv1[j] + (pv1[j] - xv1[j]) * c1[j]);
    u32x4 pk;
#pragma unroll
    for (int j = 0; j < 4; ++j) pk[j] = (unsigned)u[2 * j] | ((unsigned)u[2 * j + 1] << 16);
    *(u32x4*)((char*)As + chunk * 1024 + lane * 16) = pk;
  }
}

// ---------------- big GEMM: 128x128 tile, K=2048, A = fused mix or plain bf16 ----
// EPI 0: RB = bf16(acc)
// EPI 1: VB = bf16(acc + (vfirst - acc)*svb)
// EPI 2: kk-norm fused: KB, AHB, BHB
// EPI 3: f32 store (final output GEMM)
template <int EPI, bool FUSED>
__global__ __launch_bounds__(256, 2) void k_gemm_big(
    const unsigned short* __restrict__ A,
    const float* __restrict__ x, const float* __restrict__ xprev,
    const float* __restrict__ coef,
    const unsigned short* __restrict__ Bt,
    float* __restrict__ outF, unsigned short* __restrict__ outB,
    const unsigned short* __restrict__ svb, const float* __restrict__ vfirst,
    const unsigned short* __restrict__ abf,
    const float* __restrict__ k_k, const float* __restrict__ k_a,
    unsigned short* __restrict__ ahb, unsigned short* __restrict__ bhb) {
  __shared__ __align__(16) unsigned short As[128][64];
  __shared__ __align__(16) unsigned short Bs[128][64];
  const int tid = threadIdx.x, lane = tid & 63, wv = tid >> 6;
  const int m0 = blockIdx.y * 128, n0 = blockIdx.x * 128;
  const int wm = (wv >> 1) * 64, wn = (wv & 1) * 64;
  const int lr = lane >> 3, lc = (lane & 7) * 8;
  f32x4 acc[4][4] = {};
  for (int kt = 0; kt < C_; kt += 64) {
    __syncthreads();
    if constexpr (FUSED) {
      stage_mix(x, xprev, coef, &As[0][0], m0, kt, wv, lane);
#pragma unroll
      for (int i = 0; i < 4; ++i) {
        int chunk = wv * 4 + i, r = chunk * 8 + lr;
        gl16(Bt + (size_t)(n0 + r) * C_ + kt + lc, (char*)&Bs[0][0] + chunk * 1024);
      }
    } else {
#pragma unroll
      for (int i = 0; i < 4; ++i) {
        int chunk = wv * 4 + i, r = chunk * 8 + lr;
        gl16(A + (size_t)(m0 + r) * C_ + kt + lc, (char*)&As[0][0] + chunk * 1024);
        gl16(Bt + (size_t)(n0 + r) * C_ + kt + lc, (char*)&Bs[0][0] + chunk * 1024);
      }
    }
    __syncthreads();
    const int rr = lane & 15;
#pragma unroll
    for (int kh = 0; kh < 2; ++kh) {
      const int kof = kh * 32 + (lane >> 4) * 8;
      bf16x8 af[4], bfv[4];
#pragma unroll
      for (int i = 0; i < 4; ++i) af[i] = *(const bf16x8*)&As[wm + i * 16 + rr][kof];
#pragma unroll
      for (int j = 0; j < 4; ++j) bfv[j] = *(const bf16x8*)&Bs[wn + j * 16 + rr][kof];
#pragma unroll
      for (int i = 0; i < 4; ++i)
#pragma unroll
        for (int j = 0; j < 4; ++j)
          acc[i][j] = __builtin_amdgcn_mfma_f32_16x16x32_bf16(af[i], bfv[j], acc[i][j], 0, 0, 0);
    }
  }
  const int cr = (lane >> 4) * 4, cc2 = lane & 15;
  if constexpr (EPI == 2) {
    float kkv[4], kav[4];
#pragma unroll
    for (int j = 0; j < 4; ++j) {
      int col = n0 + wn + j * 16 + cc2;
      kkv[j] = k_k[col];
      kav[j] = k_a[col];
    }
#pragma unroll
    for (int i = 0; i < 4; ++i)
#pragma unroll
      for (int q = 0; q < 4; ++q) {
        int row = m0 + wm + i * 16 + cr + q;
        float kk4[4], p = 0.f;
#pragma unroll
        for (int j = 0; j < 4; ++j) {
          float kkc = acc[i][j][q] * kkv[j];
          kk4[j] = kkc;
          p += kkc * kkc;
        }
        p += __shfl_xor(p, 1); p += __shfl_xor(p, 2);
        p += __shfl_xor(p, 4); p += __shfl_xor(p, 8);
        float inv = 1.f / fmaxf(sqrtf(p), 1e-12f);
#pragma unroll
        for (int j = 0; j < 4; ++j) {
          int col = n0 + wn + j * 16 + cc2;
          size_t off = (size_t)row * C_ + col;
          float kkn = kk4[j] * inv;
          float a = bf2f(abf[off]);
          ahb[off] = f2bf(-kkn);
          bhb[off] = f2bf(kkn * a);
          outB[off] = f2bf(acc[i][j][q] * (1.f + (a - 1.f) * kav[j]));
        }
      }
  } else {
#pragma unroll
    for (int i = 0; i < 4; ++i)
#pragma unroll
      for (int j = 0; j < 4; ++j)
#pragma unroll
        for (int q = 0; q < 4; ++q) {
          int row = m0 + wm + i * 16 + cr + q;
          int col = n0 + wn + j * 16 + cc2;
          size_t off = (size_t)row * C_ + col;
          float v = acc[i][j][q];
          if constexpr (EPI == 0) {
            outB[off] = f2bf(v);
          } else if constexpr (EPI == 1) {
            float s = bf2f(svb[off]);
            outB[off] = f2bf(v + (vfirst[off] - v) * s);
          } else {
            outF[off] = v;
          }
        }
  }
}

// ---------------- down GEMM: H(bf16, MxN) = act(mix(x) @ Bt^T), N in {32,64,128} --
// ACT: 0 none, 1 tanh, 2 sigmoid
template <int N, int ACT>
__global__ __launch_bounds__(256, 2) void k_down(
    const float* __restrict__ x, const float* __restrict__ xprev,
    const float* __restrict__ coef, const unsigned short* __restrict__ Bt,
    unsigned short* __restrict__ out) {
  __shared__ __align__(16) unsigned short As[128][64];
  __shared__ __align__(16) unsigned short Bs[N][64];
  const int tid = threadIdx.x, lane = tid & 63, wv = tid >> 6;
  const int m0 = blockIdx.x * 128;
  const int wm = wv * 32;
  const int lr = lane >> 3, lc = (lane & 7) * 8;
  f32x4 acc[2][N / 16] = {};
  for (int kt = 0; kt < C_; kt += 64) {
    __syncthreads();
    stage_mix(x, xprev, coef, &As[0][0], m0, kt, wv, lane);
#pragma unroll
    for (int i = 0; i < N / 32; ++i) {
      int chunk = wv * (N / 32) + i, r = chunk * 8 + lr;
      gl16(Bt + (size_t)r * C_ + kt + lc, (char*)&Bs[0][0] + chunk * 1024);
    }
    __syncthreads();
    const int rr = lane & 15;
#pragma unroll
    for (int kh = 0; kh < 2; ++kh) {
      const int kof = kh * 32 + (lane >> 4) * 8;
      bf16x8 af[2], bfv[N / 16];
#pragma unroll
      for (int i = 0; i < 2; ++i) af[i] = *(const bf16x8*)&As[wm + i * 16 + rr][kof];
#pragma unroll
      for (int j = 0; j < N / 16; ++j) bfv[j] = *(const bf16x8*)&Bs[j * 16 + rr][kof];
#pragma unroll
      for (int i = 0; i < 2; ++i)
#pragma unroll
        for (int j = 0; j < N / 16; ++j)
          acc[i][j] = __builtin_amdgcn_mfma_f32_16x16x32_bf16(af[i], bfv[j], acc[i][j], 0, 0, 0);
    }
  }
  const int cr = (lane >> 4) * 4, cc2 = lane & 15;
#pragma unroll
  for (int i = 0; i < 2; ++i)
#pragma unroll
    for (int j = 0; j < N / 16; ++j)
#pragma unroll
      for (int q = 0; q < 4; ++q) {
        int row = m0 + wm + i * 16 + cr + q;
        int col = j * 16 + cc2;
        float v = acc[i][j][q];
        if (ACT == 1) v = tanhf(v);
        else if (ACT == 2) v = 1.f / (1.f + expf(-v));
        out[(size_t)row * N + col] = f2bf(v);
      }
}

// ---------------- up GEMM (K in {32,64,128}), single K pass ----------------
// MODE 0: wd = exp(-exp(-softplus(-(bias+up)) - 0.5)) -> outF (f32)
// MODE 1: sigmoid(bias+up) -> outB (bf16)
// MODE 3: up -> outB (bf16)
template <int K, int MODE>
__global__ __launch_bounds__(256, 2) void k_up(
    const unsigned short* __restrict__ A, const unsigned short* __restrict__ Bt,
    const float* __restrict__ bias, float* __restrict__ outF,
    unsigned short* __restrict__ outB) {
  __shared__ __align__(16) unsigned short As[128][K];
  __shared__ __align__(16) unsigned short Bs[128][K];
  const int tid = threadIdx.x, lane = tid & 63, wv = tid >> 6;
  const int m0 = blockIdx.y * 128, n0 = blockIdx.x * 128;
  const int wm = (wv >> 1) * 64, wn = (wv & 1) * 64;
  constexpr int LPR = K / 8;
  constexpr int RPC = 64 / LPR;
  const int lr = lane / LPR, lc = (lane % LPR) * 8;
  f32x4 acc[4][4] = {};
#pragma unroll
  for (int i = 0; i < K / 16; ++i) {
    int chunk = wv * (K / 16) + i;
    int r = chunk * RPC + lr;
    gl16(A + (size_t)(m0 + r) * K + lc, (char*)&As[0][0] + chunk * 1024);
    gl16(Bt + (size_t)(n0 + r) * K + lc, (char*)&Bs[0][0] + chunk * 1024);
  }
  __syncthreads();
  const int rr = lane & 15;
#pragma unroll
  for (int ks = 0; ks < K / 32; ++ks) {
    const int kof = ks * 32 + (lane >> 4) * 8;
    bf16x8 af[4], bfv[4];
#pragma unroll
    for (int i = 0; i < 4; ++i) af[i] = *(const bf16x8*)&As[wm + i * 16 + rr][kof];
#pragma unroll
    for (int j = 0; j < 4; ++j) bfv[j] = *(const bf16x8*)&Bs[wn + j * 16 + rr][kof];
#pragma unroll
    for (int i = 0; i < 4; ++i)
#pragma unroll
      for (int j = 0; j < 4; ++j)
        acc[i][j] = __builtin_amdgcn_mfma_f32_16x16x32_bf16(af[i], bfv[j], acc[i][j], 0, 0, 0);
  }
  const int cr = (lane >> 4) * 4, cc2 = lane & 15;
#pragma unroll
  for (int i = 0; i < 4; ++i)
#pragma unroll
    for (int j = 0; j < 4; ++j)
#pragma unroll
      for (int q = 0; q < 4; ++q) {
        int row = m0 + wm + i * 16 + cr + q;
        int col = n0 + wn + j * 16 + cc2;
        size_t off = (size_t)row * C_ + col;
        float up = acc[i][j][q];
        if (MODE == 0) {
          float z = -(bias[col] + up);
          float sp = fmaxf(z, 0.f) + log1pf(expf(-fabsf(z)));
          outF[off] = expf(-expf(-sp - 0.5f));
        } else if (MODE == 1) {
          outB[off] = f2bf(1.f / (1.f + expf(-(bias[col] + up))));
        } else {
          outB[off] = f2bf(up);
        }
      }
}

// ---------------- WKV recurrent scan: register-only, no barriers ----------------
// 1024 one-wave blocks. Block p: wr = p>>7 (row-octet), bh = p&127 (same-XCD
// grouping for the 8 waves of one (b,h) under round-robin XCD dispatch).
// Lane: rl = lane>>3 (local row), e = lane&7 (elem octet). State: 8 f32/lane.
// 4 named register slots, depth-3 prefetch, compiler-managed waitcnts.
__global__ __launch_bounds__(64) void k_scan(
    const unsigned short* __restrict__ RB, const float* __restrict__ WD,
    const unsigned short* __restrict__ KB, const unsigned short* __restrict__ VB,
    const unsigned short* __restrict__ AHB, const unsigned short* __restrict__ BHB,
    const float* __restrict__ s0, float* __restrict__ out) {
  const int lane = threadIdx.x & 63;
  const int p = blockIdx.x;
  const int wr = p >> 7, bh = p & 127;
  const int b = bh >> 5, h = bh & 31;
  const int e = lane & 7, rl = lane >> 3;
  const int row = wr * 8 + rl;
  const int e8 = e * 8;
  const size_t base = (size_t)b * T_ * C_ + h * 64;  // elem offset at t=0
  float S[8];
  {
    const float* sp = s0 + ((size_t)(b * H_ + h) * 64 + row) * 64 + e8;
    f32x4 s0v = *(const f32x4*)sp, s1v = *(const f32x4*)(sp + 4);
#pragma unroll
    for (int j = 0; j < 4; ++j) { S[j] = s0v[j]; S[4 + j] = s1v[j]; }
  }

#define DECL_SLOT(n) bf16x8 r##n, k##n, a##n, bb##n; f32x4 wA##n, wB##n; unsigned short v##n;
  DECL_SLOT(0) DECL_SLOT(1) DECL_SLOT(2) DECL_SLOT(3)

#define ISSUE(n, t)                                              \
  {                                                              \
    int ti = (t) < T_ ? (t) : T_ - 1;                            \
    size_t eo = base + (size_t)ti * C_;                          \
    size_t ee = eo + e8;                                         \
    r##n = *(const bf16x8*)(RB + ee);                            \
    k##n = *(const bf16x8*)(KB + ee);                            \
    a##n = *(const bf16x8*)(AHB + ee);                           \
    bb##n = *(const bf16x8*)(BHB + ee);                          \
    wA##n = *(const f32x4*)(WD + ee);                            \
    wB##n = *(const f32x4*)(WD + ee + 4);                        \
    v##n = VB[eo + row];                                         \
  }

#define STEP(n, t)                                               \
  {                                                              \
    float rr[8], kk[8], aa[8], bv[8], ww[8];                     \
    _Pragma("unroll") for (int j = 0; j < 8; ++j) {              \
      rr[j] = (float)r##n[j];                                    \
      kk[j] = (float)k##n[j];                                    \
      aa[j] = (float)a##n[j];                                    \
      bv[j] = (float)bb##n[j];                                   \
    }                                                            \
    _Pragma("unroll") for (int j = 0; j < 4; ++j) {              \
      ww[j] = wA##n[j];                                          \
      ww[4 + j] = wB##n[j];                                      \
    }                                                            \
    float sa0 = S[0] * aa[0], sa1 = S[1] * aa[1];                \
    _Pragma("unroll") for (int j = 2; j < 8; j += 2) {           \
      sa0 = fmaf(S[j], aa[j], sa0);                              \
      sa1 = fmaf(S[j + 1], aa[j + 1], sa1);                      \
    }                                                            \
    float sa = qsum(sa0 + sa1);                                  \
    sa += __shfl_xor(sa, 4);                                     \
    float vi = bf2f(v##n);                                       \
    float o0 = 0.f, o1 = 0.f;                                    \
    _Pragma("unroll") for (int j = 0; j < 8; j += 2) {           \
      S[j] = fmaf(S[j], ww[j], fmaf(sa, bv[j], vi * kk[j]));     \
      S[j + 1] = fmaf(S[j + 1], ww[j + 1],                       \
                      fmaf(sa, bv[j + 1], vi * kk[j + 1]));      \
      o0 = fmaf(S[j], rr[j], o0);                                \
      o1 = fmaf(S[j + 1], rr[j + 1], o1);                        \
    }                                                            \
    float o = qsum(o0 + o1);                                     \
    o += __shfl_xor(o, 4);                                       \
    if (e == 0) out[base + (size_t)(t) * C_ + row] = o;          \
  }

  ISSUE(0, 0) ISSUE(1, 1) ISSUE(2, 2)
#pragma unroll 1
  for (int t = 0; t < T_; t += 4) {
    ISSUE(3, t + 3) STEP(0, t)
    ISSUE(0, t + 4) STEP(1, t + 1)
    ISSUE(1, t + 5) STEP(2, t + 2)
    ISSUE(2, t + 6) STEP(3, t + 3)
  }
#undef DECL_SLOT
#undef ISSUE
#undef STEP
}

// ---------------- GroupNorm + bonus + gate (wave per (b,t,h)) ----------------
__global__ __launch_bounds__(256) void k_gn(
    const float* __restrict__ o, const unsigned short* __restrict__ rb,
    const unsigned short* __restrict__ kb, const unsigned short* __restrict__ v,
    const unsigned short* __restrict__ g, const float* __restrict__ r_k,
    const float* __restrict__ lnw, const float* __restrict__ lnb,
    unsigned short* __restrict__ outg) {
  int wid = blockIdx.x * 4 + (threadIdx.x >> 6);
  int lane = threadIdx.x & 63;
  int h = wid & (H_ - 1);
  size_t bt = (size_t)(wid >> 5);
  size_t off = bt * C_ + h * 64 + lane;
  int c = h * 64 + lane;
  float x = o[off];
  float mu = x;
#pragma unroll
  for (int m = 1; m < 64; m <<= 1) mu += __shfl_xor(mu, m);
  mu *= (1.f / 64.f);
  float d = x - mu;
  float var = d * d;
#pragma unroll
  for (int m = 1; m < 64; m <<= 1) var += __shfl_xor(var, m);
  var *= (1.f / 64.f);
  float y = d * rsqrtf(var + 6.4e-4f) * lnw[c] + lnb[c];
  float bd = bf2f(rb[off]) * bf2f(kb[off]) * r_k[c];
#pragma unroll
  for (int m = 1; m < 64; m <<= 1) bd += __shfl_xor(bd, m);
  float res = (y + bd * bf2f(v[off])) * bf2f(g[off]);
  outg[off] = f2bf(res);
}

// ---------------- host launch ----------------
extern "C" void kernel_launch(void* const* d_in, const int* in_sizes, int n_in,
                              void* d_out, int out_size, void* d_ws, size_t ws_size,
                              hipStream_t stream) {
  const float* x      = (const float*)d_in[0];
  const float* vfirst = (const float*)d_in[1];
  const float* xprev  = (const float*)d_in[2];
  const float* wkv0   = (const float*)d_in[3];
  const float* x_r = (const float*)d_in[4];
  const float* x_w = (const float*)d_in[5];
  const float* x_k = (const float*)d_in[6];
  const float* x_v = (const float*)d_in[7];
  const float* x_a = (const float*)d_in[8];
  const float* x_g = (const float*)d_in[9];
  const float* w0 = (const float*)d_in[10];
  const float* w1 = (const float*)d_in[11];
  const float* w2 = (const float*)d_in[12];
  const float* a0 = (const float*)d_in[13];
  const float* a1 = (const float*)d_in[14];
  const float* a2 = (const float*)d_in[15];
  const float* v0 = (const float*)d_in[16];
  const float* v1 = (const float*)d_in[17];
  const float* v2 = (const float*)d_in[18];
  const float* g1 = (const float*)d_in[19];
  const float* g2 = (const float*)d_in[20];
  const float* k_k = (const float*)d_in[21];
  const float* k_a = (const float*)d_in[22];
  const float* r_k = (const float*)d_in[23];
  const float* Wr = (const float*)d_in[24];
  const float* Wk = (const float*)d_in[25];
  const float* Wv = (const float*)d_in[26];
  const float* Wo = (const float*)d_in[27];
  const float* lnw = (const float*)d_in[28];
  const float* lnb = (const float*)d_in[29];
  float* out = (float*)d_out;
  char* ws = (char*)d_ws;

  // ---- workspace layout (~239 MiB) ----
  size_t woff = 0;
  auto alloc = [&](size_t n) { char* p = ws + woff; woff += n; return p; };
  char* R1 = alloc(67108864);                       // ABF|SVB -> WD (f32)
  unsigned short* ABF = (unsigned short*)R1;
  unsigned short* SVB = (unsigned short*)(R1 + 33554432);
  float* WD = (float*)R1;
  unsigned short* WT  = (unsigned short*)alloc(8388608);   // transposed big weight
  unsigned short* W1T = (unsigned short*)alloc(262144);
  unsigned short* A1T = (unsigned short*)alloc(262144);
  unsigned short* V1T = (unsigned short*)alloc(131072);
  unsigned short* G1T = (unsigned short*)alloc(524288);
  unsigned short* W2T = (unsigned short*)alloc(262144);
  unsigned short* A2T = (unsigned short*)alloc(262144);
  unsigned short* V2T = (unsigned short*)alloc(131072);
  unsigned short* G2T = (unsigned short*)alloc(524288);
  unsigned short* HWB = (unsigned short*)alloc(1048576);
  unsigned short* HAB = (unsigned short*)alloc(1048576);
  unsigned short* HVB = (unsigned short*)alloc(524288);
  unsigned short* HGB = (unsigned short*)alloc(2097152);
  unsigned short* RB  = (unsigned short*)alloc(33554432);
  unsigned short* KB  = (unsigned short*)alloc(33554432);
  unsigned short* VB  = (unsigned short*)alloc(33554432);
  unsigned short* AHB = (unsigned short*)alloc(33554432);
  unsigned short* BHB = (unsigned short*)alloc(33554432);
  unsigned short* GBF  = AHB;  // post-scan overlay (AHB dead)
  unsigned short* OUTG = BHB;  // post-scan overlay (BHB dead)

  dim3 blk(256);
  dim3 gg(16, 64);

  // small weight transposes (K-contiguous layouts)
  k_transpose<<<dim3(2, 64), blk, 0, stream>>>(w1, W1T, 2048, 64);
  k_transpose<<<dim3(2, 64), blk, 0, stream>>>(a1, A1T, 2048, 64);
  k_transpose<<<dim3(1, 64), blk, 0, stream>>>(v1, V1T, 2048, 32);
  k_transpose<<<dim3(4, 64), blk, 0, stream>>>(g1, G1T, 2048, 128);
  k_transpose<<<dim3(64, 2), blk, 0, stream>>>(w2, W2T, 64, 2048);
  k_transpose<<<dim3(64, 2), blk, 0, stream>>>(a2, A2T, 64, 2048);
  k_transpose<<<dim3(64, 1), blk, 0, stream>>>(v2, V2T, 32, 2048);
  k_transpose<<<dim3(64, 4), blk, 0, stream>>>(g2, G2T, 128, 2048);

  // a-chain, v-chain (need ABF / SVB before K/V projections)
  k_down<64, 0><<<dim3(64), blk, 0, stream>>>(x, xprev, x_a, A1T, HAB);
  k_up<64, 1><<<gg, blk, 0, stream>>>(HAB, A2T, a0, nullptr, ABF);
  k_down<32, 0><<<dim3(64), blk, 0, stream>>>(x, xprev, x_v, V1T, HVB);
  k_up<32, 1><<<gg, blk, 0, stream>>>(HVB, V2T, v0, nullptr, SVB);

  // projections (WT slot reused; fused-mix A staging)
  k_transpose<<<dim3(64, 64), blk, 0, stream>>>(Wr, WT, 2048, 2048);
  k_gemm_big<0, true><<<gg, blk, 0, stream>>>(nullptr, x, xprev, x_r, WT,
      nullptr, RB, nullptr, nullptr, nullptr, nullptr, nullptr, nullptr, nullptr);
  k_transpose<<<dim3(64, 64), blk, 0, stream>>>(Wv, WT, 2048, 2048);
  k_gemm_big<1, true><<<gg, blk, 0, stream>>>(nullptr, x, xprev, x_v, WT,
      nullptr, VB, SVB, vfirst, nullptr, nullptr, nullptr, nullptr, nullptr);
  k_transpose<<<dim3(64, 64), blk, 0, stream>>>(Wk, WT, 2048, 2048);
  k_gemm_big<2, true><<<gg, blk, 0, stream>>>(nullptr, x, xprev, x_k, WT,
      nullptr, KB, nullptr, nullptr, ABF, k_k, k_a, AHB, BHB);

  // w-chain (ABF/SVB dead -> WD overlays them)
  k_down<64, 1><<<dim3(64), blk, 0, stream>>>(x, xprev, x_w, W1T, HWB);
  k_up<64, 0><<<gg, blk, 0, stream>>>(HWB, W2T, w0, WD, nullptr);

  // recurrent scan (register-only, no barriers; writes scan-out to d_out)
  k_scan<<<dim3(1024), dim3(64), 0, stream>>>(RB, WD, KB, VB, AHB, BHB, wkv0, out);

  // g-chain (post-scan; GBF overlays AHB)
  k_down<128, 2><<<dim3(64), blk, 0, stream>>>(x, xprev, x_g, G1T, HGB);
  k_up<128, 3><<<gg, blk, 0, stream>>>(HGB, G2T, nullptr, nullptr, GBF);

  // GroupNorm + bonus + gate (OUTG overlays BHB)
  k_gn<<<dim3(65536), blk, 0, stream>>>(out, RB, KB, VB, GBF, r_k, lnw, lnb, OUTG);

  // final projection
  k_transpose<<<dim3(64, 64), blk, 0, stream>>>(Wo, WT, 2048, 2048);
  k_gemm_big<3, false><<<gg, blk, 0, stream>>>(OUTG, nullptr, nullptr, nullptr, WT,
      out, nullptr, nullptr, nullptr, nullptr, nullptr, nullptr, nullptr, nullptr);
}

// Round 4
// 1831.930 us; speedup vs baseline: 1.6367x; 1.1754x over previous
//
#include <hip/hip_runtime.h>

typedef float f32x4 __attribute__((ext_vector_type(4)));
typedef __bf16 bf16x8 __attribute__((ext_vector_type(8)));
typedef __bf16 bf16x4 __attribute__((ext_vector_type(4)));
typedef unsigned int u32x4 __attribute__((ext_vector_type(4)));

#define DI __device__ __forceinline__

constexpr int B_ = 4, T_ = 2048, C_ = 2048, H_ = 32;
constexpr int M_ = B_ * T_;  // 8192 rows

DI unsigned short f2bf(float f) {
  unsigned u = __float_as_uint(f);
  return (unsigned short)((u + 0x7FFFu + ((u >> 16) & 1u)) >> 16);
}
DI float bf2f(unsigned short h) { return __uint_as_float(((unsigned)h) << 16); }

DI void gl16(const void* g, void* l) {
  __builtin_amdgcn_global_load_lds(
      (__attribute__((address_space(1))) const unsigned int*)g,
      (__attribute__((address_space(3))) unsigned int*)l, 16, 0, 0);
}

// 16-lane sum, pure DPP (no LDS pipe): quad_perm pair -> quad-uniform,
// then row_ror:4 + row_ror:8 accumulate the 4 quad totals into all 16 lanes.
DI float rsum16(float x) {
  int t = __builtin_amdgcn_update_dpp(0, __float_as_int(x), 0xB1, 0xF, 0xF, true);
  x += __int_as_float(t);
  t = __builtin_amdgcn_update_dpp(0, __float_as_int(x), 0x4E, 0xF, 0xF, true);
  x += __int_as_float(t);
  t = __builtin_amdgcn_update_dpp(0, __float_as_int(x), 0x124, 0xF, 0xF, true);
  x += __int_as_float(t);
  t = __builtin_amdgcn_update_dpp(0, __float_as_int(x), 0x128, 0xF, 0xF, true);
  x += __int_as_float(t);
  return x;
}

// ---------------- transpose f32 (R x C) -> bf16 (C x R) ----------------
__global__ __launch_bounds__(256) void k_transpose(const float* __restrict__ in,
                                                   unsigned short* __restrict__ out,
                                                   int R, int C) {
  __shared__ float tile[32][33];
  int c0 = blockIdx.x * 32, r0 = blockIdx.y * 32;
  int tx = threadIdx.x & 31, ty = threadIdx.x >> 5;
#pragma unroll
  for (int i = 0; i < 4; ++i) {
    int r = r0 + ty * 4 + i, c = c0 + tx;
    if (r < R && c < C) tile[ty * 4 + i][tx] = in[(size_t)r * C + c];
  }
  __syncthreads();
#pragma unroll
  for (int i = 0; i < 4; ++i) {
    int c = c0 + ty * 4 + i, r = r0 + tx;
    if (r < R && c < C) out[(size_t)c * R + r] = f2bf(tile[tx][ty * 4 + i]);
  }
}

// ---------------- token-shift mix prep (1 or 2 coef sets) ----------------
DI void mix_emit(const float* coef, int c0, size_t off,
                 const float* xv, const float* dx, unsigned short* dst) {
  unsigned short u[8];
#pragma unroll
  for (int i = 0; i < 2; ++i) {
    f32x4 cf = *(const f32x4*)(coef + c0 + i * 4);
#pragma unroll
    for (int j = 0; j < 4; ++j) u[i * 4 + j] = f2bf(xv[i * 4 + j] + dx[i * 4 + j] * cf[j]);
  }
  u32x4 pv;
#pragma unroll
  for (int j = 0; j < 4; ++j) pv[j] = (unsigned)u[2 * j] | ((unsigned)u[2 * j + 1] << 16);
  *(u32x4*)(dst + off) = pv;
}

__global__ __launch_bounds__(256) void k_prep2(
    const float* __restrict__ x, const float* __restrict__ xprev,
    const float* __restrict__ cA, const float* __restrict__ cB,
    unsigned short* __restrict__ XA, unsigned short* __restrict__ XB) {
  int bt = blockIdx.x;
  int t = bt & (T_ - 1);
  int c0 = threadIdx.x * 8;
  size_t off = (size_t)bt * C_ + c0;
  const float* xp = x + off;
  const float* pp = t ? (xp - C_) : (xprev + (size_t)(bt >> 11) * C_ + c0);
  float xv[8], dx[8];
#pragma unroll
  for (int i = 0; i < 2; ++i) {
    f32x4 a = *(const f32x4*)(xp + i * 4);
    f32x4 p = *(const f32x4*)(pp + i * 4);
#pragma unroll
    for (int j = 0; j < 4; ++j) { xv[i * 4 + j] = a[j]; dx[i * 4 + j] = p[j] - a[j]; }
  }
  mix_emit(cA, c0, off, xv, dx, XA);
  mix_emit(cB, c0, off, xv, dx, XB);
}

__global__ __launch_bounds__(256) void k_prep1(
    const float* __restrict__ x, const float* __restrict__ xprev,
    const float* __restrict__ cA, unsigned short* __restrict__ XA) {
  int bt = blockIdx.x;
  int t = bt & (T_ - 1);
  int c0 = threadIdx.x * 8;
  size_t off = (size_t)bt * C_ + c0;
  const float* xp = x + off;
  const float* pp = t ? (xp - C_) : (xprev + (size_t)(bt >> 11) * C_ + c0);
  float xv[8], dx[8];
#pragma unroll
  for (int i = 0; i < 2; ++i) {
    f32x4 a = *(const f32x4*)(xp + i * 4);
    f32x4 p = *(const f32x4*)(pp + i * 4);
#pragma unroll
    for (int j = 0; j < 4; ++j) { xv[i * 4 + j] = a[j]; dx[i * 4 + j] = p[j] - a[j]; }
  }
  mix_emit(cA, c0, off, xv, dx, XA);
}

// fused token-shift mix staging (for small down-GEMMs only)
DI void stage_mix(const float* __restrict__ x, const float* __restrict__ xprev,
                  const float* __restrict__ coef, unsigned short* As,
                  int m0, int kt, int wv, int lane) {
  const int lr = lane >> 3, lc = (lane & 7) * 8;
  f32x4 c0 = *(const f32x4*)(coef + kt + lc);
  f32x4 c1 = *(const f32x4*)(coef + kt + lc + 4);
#pragma unroll
  for (int i = 0; i < 4; ++i) {
    int chunk = wv * 4 + i;
    int r = chunk * 8 + lr;
    int m = m0 + r;
    const float* xp = x + (size_t)m * C_ + kt + lc;
    const float* pp = (m & (T_ - 1)) ? (xp - C_)
                                     : (xprev + (size_t)(m >> 11) * C_ + kt + lc);
    f32x4 xv0 = *(const f32x4*)xp, xv1 = *(const f32x4*)(xp + 4);
    f32x4 pv0 = *(const f32x4*)pp, pv1 = *(const f32x4*)(pp + 4);
    unsigned short u[8];
#pragma unroll
    for (int j = 0; j < 4; ++j) u[j] = f2bf(xv0[j] + (pv0[j] - xv0[j]) * c0[j]);
#pragma unroll
    for (int j = 0; j < 4; ++j) u[4 + j] = f2bf(xv1[j] + (pv1[j] - xv1[j]) * c1[j]);
    u32x4 pk;
#pragma unroll
    for (int j = 0; j < 4; ++j) pk[j] = (unsigned)u[2 * j] | ((unsigned)u[2 * j + 1] << 16);
    *(u32x4*)((char*)As + chunk * 1024 + lane * 16) = pk;
  }
}

// ---------------- big GEMM: 128x128 tile, K=2048, plain bf16 A (gl16 staging) ----
// EPI 0: RB = bf16(acc)
// EPI 1: VB = bf16(acc + (vfirst - acc)*svb)
// EPI 2: kk-norm fused: KB, AHB, BHB
// EPI 3: f32 store (final output GEMM)
template <int EPI>
__global__ __launch_bounds__(256, 2) void k_gemm_big(
    const unsigned short* __restrict__ A,
    const unsigned short* __restrict__ Bt,
    float* __restrict__ outF, unsigned short* __restrict__ outB,
    const unsigned short* __restrict__ svb, const float* __restrict__ vfirst,
    const unsigned short* __restrict__ abf,
    const float* __restrict__ k_k, const float* __restrict__ k_a,
    unsigned short* __restrict__ ahb, unsigned short* __restrict__ bhb) {
  __shared__ __align__(16) unsigned short As[128][64];
  __shared__ __align__(16) unsigned short Bs[128][64];
  const int tid = threadIdx.x, lane = tid & 63, wv = tid >> 6;
  const int m0 = blockIdx.y * 128, n0 = blockIdx.x * 128;
  const int wm = (wv >> 1) * 64, wn = (wv & 1) * 64;
  const int lr = lane >> 3, lc = (lane & 7) * 8;
  f32x4 acc[4][4] = {};
  for (int kt = 0; kt < C_; kt += 64) {
    __syncthreads();
#pragma unroll
    for (int i = 0; i < 4; ++i) {
      int chunk = wv * 4 + i, r = chunk * 8 + lr;
      gl16(A + (size_t)(m0 + r) * C_ + kt + lc, (char*)&As[0][0] + chunk * 1024);
      gl16(Bt + (size_t)(n0 + r) * C_ + kt + lc, (char*)&Bs[0][0] + chunk * 1024);
    }
    __syncthreads();
    const int rr = lane & 15;
#pragma unroll
    for (int kh = 0; kh < 2; ++kh) {
      const int kof = kh * 32 + (lane >> 4) * 8;
      bf16x8 af[4], bfv[4];
#pragma unroll
      for (int i = 0; i < 4; ++i) af[i] = *(const bf16x8*)&As[wm + i * 16 + rr][kof];
#pragma unroll
      for (int j = 0; j < 4; ++j) bfv[j] = *(const bf16x8*)&Bs[wn + j * 16 + rr][kof];
#pragma unroll
      for (int i = 0; i < 4; ++i)
#pragma unroll
        for (int j = 0; j < 4; ++j)
          acc[i][j] = __builtin_amdgcn_mfma_f32_16x16x32_bf16(af[i], bfv[j], acc[i][j], 0, 0, 0);
    }
  }
  const int cr = (lane >> 4) * 4, cc2 = lane & 15;
  if constexpr (EPI == 2) {
    float kkv[4], kav[4];
#pragma unroll
    for (int j = 0; j < 4; ++j) {
      int col = n0 + wn + j * 16 + cc2;
      kkv[j] = k_k[col];
      kav[j] = k_a[col];
    }
#pragma unroll
    for (int i = 0; i < 4; ++i)
#pragma unroll
      for (int q = 0; q < 4; ++q) {
        int row = m0 + wm + i * 16 + cr + q;
        float kk4[4], p = 0.f;
#pragma unroll
        for (int j = 0; j < 4; ++j) {
          float kkc = acc[i][j][q] * kkv[j];
          kk4[j] = kkc;
          p += kkc * kkc;
        }
        p += __shfl_xor(p, 1); p += __shfl_xor(p, 2);
        p += __shfl_xor(p, 4); p += __shfl_xor(p, 8);
        float inv = 1.f / fmaxf(sqrtf(p), 1e-12f);
#pragma unroll
        for (int j = 0; j < 4; ++j) {
          int col = n0 + wn + j * 16 + cc2;
          size_t off = (size_t)row * C_ + col;
          float kkn = kk4[j] * inv;
          float a = bf2f(abf[off]);
          ahb[off] = f2bf(-kkn);
          bhb[off] = f2bf(kkn * a);
          outB[off] = f2bf(acc[i][j][q] * (1.f + (a - 1.f) * kav[j]));
        }
      }
  } else {
#pragma unroll
    for (int i = 0; i < 4; ++i)
#pragma unroll
      for (int j = 0; j < 4; ++j)
#pragma unroll
        for (int q = 0; q < 4; ++q) {
          int row = m0 + wm + i * 16 + cr + q;
          int col = n0 + wn + j * 16 + cc2;
          size_t off = (size_t)row * C_ + col;
          float v = acc[i][j][q];
          if constexpr (EPI == 0) {
            outB[off] = f2bf(v);
          } else if constexpr (EPI == 1) {
            float s = bf2f(svb[off]);
            outB[off] = f2bf(v + (vfirst[off] - v) * s);
          } else {
            outF[off] = v;
          }
        }
  }
}

// ---------------- down GEMM: H(bf16, MxN) = act(mix @ Bt^T), N in {32,64,128} --
// ACT: 0 none, 1 tanh, 2 sigmoid. FUSED: compute mix on the fly vs plain bf16 A.
template <int N, int ACT, bool FUSED>
__global__ __launch_bounds__(256, 2) void k_down(
    const unsigned short* __restrict__ A,
    const float* __restrict__ x, const float* __restrict__ xprev,
    const float* __restrict__ coef, const unsigned short* __restrict__ Bt,
    unsigned short* __restrict__ out) {
  __shared__ __align__(16) unsigned short As[128][64];
  __shared__ __align__(16) unsigned short Bs[N][64];
  const int tid = threadIdx.x, lane = tid & 63, wv = tid >> 6;
  const int m0 = blockIdx.x * 128;
  const int wm = wv * 32;
  const int lr = lane >> 3, lc = (lane & 7) * 8;
  f32x4 acc[2][N / 16] = {};
  for (int kt = 0; kt < C_; kt += 64) {
    __syncthreads();
    if constexpr (FUSED) {
      stage_mix(x, xprev, coef, &As[0][0], m0, kt, wv, lane);
    } else {
#pragma unroll
      for (int i = 0; i < 4; ++i) {
        int chunk = wv * 4 + i, r = chunk * 8 + lr;
        gl16(A + (size_t)(m0 + r) * C_ + kt + lc, (char*)&As[0][0] + chunk * 1024);
      }
    }
#pragma unroll
    for (int i = 0; i < N / 32; ++i) {
      int chunk = wv * (N / 32) + i, r = chunk * 8 + lr;
      gl16(Bt + (size_t)r * C_ + kt + lc, (char*)&Bs[0][0] + chunk * 1024);
    }
    __syncthreads();
    const int rr = lane & 15;
#pragma unroll
    for (int kh = 0; kh < 2; ++kh) {
      const int kof = kh * 32 + (lane >> 4) * 8;
      bf16x8 af[2], bfv[N / 16];
#pragma unroll
      for (int i = 0; i < 2; ++i) af[i] = *(const bf16x8*)&As[wm + i * 16 + rr][kof];
#pragma unroll
      for (int j = 0; j < N / 16; ++j) bfv[j] = *(const bf16x8*)&Bs[j * 16 + rr][kof];
#pragma unroll
      for (int i = 0; i < 2; ++i)
#pragma unroll
        for (int j = 0; j < N / 16; ++j)
          acc[i][j] = __builtin_amdgcn_mfma_f32_16x16x32_bf16(af[i], bfv[j], acc[i][j], 0, 0, 0);
    }
  }
  const int cr = (lane >> 4) * 4, cc2 = lane & 15;
#pragma unroll
  for (int i = 0; i < 2; ++i)
#pragma unroll
    for (int j = 0; j < N / 16; ++j)
#pragma unroll
      for (int q = 0; q < 4; ++q) {
        int row = m0 + wm + i * 16 + cr + q;
        int col = j * 16 + cc2;
        float v = acc[i][j][q];
        if (ACT == 1) v = tanhf(v);
        else if (ACT == 2) v = 1.f / (1.f + expf(-v));
        out[(size_t)row * N + col] = f2bf(v);
      }
}

// ---------------- up GEMM (K in {32,64,128}), single K pass ----------------
// MODE 0: wd = exp(-exp(-softplus(-(bias+up)) - 0.5)) -> outF (f32)
// MODE 1: sigmoid(bias+up) -> outB (bf16)
// MODE 3: up -> outB (bf16)
template <int K, int MODE>
__global__ __launch_bounds__(256, 2) void k_up(
    const unsigned short* __restrict__ A, const unsigned short* __restrict__ Bt,
    const float* __restrict__ bias, float* __restrict__ outF,
    unsigned short* __restrict__ outB) {
  __shared__ __align__(16) unsigned short As[128][K];
  __shared__ __align__(16) unsigned short Bs[128][K];
  const int tid = threadIdx.x, lane = tid & 63, wv = tid >> 6;
  const int m0 = blockIdx.y * 128, n0 = blockIdx.x * 128;
  const int wm = (wv >> 1) * 64, wn = (wv & 1) * 64;
  constexpr int LPR = K / 8;
  constexpr int RPC = 64 / LPR;
  const int lr = lane / LPR, lc = (lane % LPR) * 8;
  f32x4 acc[4][4] = {};
#pragma unroll
  for (int i = 0; i < K / 16; ++i) {
    int chunk = wv * (K / 16) + i;
    int r = chunk * RPC + lr;
    gl16(A + (size_t)(m0 + r) * K + lc, (char*)&As[0][0] + chunk * 1024);
    gl16(Bt + (size_t)(n0 + r) * K + lc, (char*)&Bs[0][0] + chunk * 1024);
  }
  __syncthreads();
  const int rr = lane & 15;
#pragma unroll
  for (int ks = 0; ks < K / 32; ++ks) {
    const int kof = ks * 32 + (lane >> 4) * 8;
    bf16x8 af[4], bfv[4];
#pragma unroll
    for (int i = 0; i < 4; ++i) af[i] = *(const bf16x8*)&As[wm + i * 16 + rr][kof];
#pragma unroll
    for (int j = 0; j < 4; ++j) bfv[j] = *(const bf16x8*)&Bs[wn + j * 16 + rr][kof];
#pragma unroll
    for (int i = 0; i < 4; ++i)
#pragma unroll
      for (int j = 0; j < 4; ++j)
        acc[i][j] = __builtin_amdgcn_mfma_f32_16x16x32_bf16(af[i], bfv[j], acc[i][j], 0, 0, 0);
  }
  const int cr = (lane >> 4) * 4, cc2 = lane & 15;
#pragma unroll
  for (int i = 0; i < 4; ++i)
#pragma unroll
    for (int j = 0; j < 4; ++j)
#pragma unroll
      for (int q = 0; q < 4; ++q) {
        int row = m0 + wm + i * 16 + cr + q;
        int col = n0 + wn + j * 16 + cc2;
        size_t off = (size_t)row * C_ + col;
        float up = acc[i][j][q];
        if (MODE == 0) {
          float z = -(bias[col] + up);
          float sp = fmaxf(z, 0.f) + log1pf(expf(-fabsf(z)));
          outF[off] = expf(-expf(-sp - 0.5f));
        } else if (MODE == 1) {
          outB[off] = f2bf(1.f / (1.f + expf(-(bias[col] + up))));
        } else {
          outB[off] = f2bf(up);
        }
      }
}

// ---------------- WKV recurrent scan: register-only, no barriers ----------------
// 2048 one-wave blocks. Block p: wr = p>>7 (row-quad 0..15), bh = p&127 (keeps
// the 16 waves of one (b,h) on one XCD under round-robin dispatch).
// Lane: rl = lane>>4 (local row 0..3), e = lane&15 (col-quad). 4 f32 state/lane.
// 4 named register slots, depth-3 prefetch; reductions are pure DPP.
__global__ __launch_bounds__(64) void k_scan(
    const unsigned short* __restrict__ RB, const float* __restrict__ WD,
    const unsigned short* __restrict__ KB, const unsigned short* __restrict__ VB,
    const unsigned short* __restrict__ AHB, const unsigned short* __restrict__ BHB,
    const float* __restrict__ s0, float* __restrict__ out) {
  const int lane = threadIdx.x & 63;
  const int p = blockIdx.x;
  const int wr = p >> 7, bh = p & 127;
  const int b = bh >> 5, h = bh & 31;
  const int e = lane & 15, rl = lane >> 4;
  const int row = wr * 4 + rl;
  const int e4 = e * 4;
  const size_t base = (size_t)b * T_ * C_ + h * 64;
  f32x4 S = *(const f32x4*)(s0 + ((size_t)(b * H_ + h) * 64 + row) * 64 + e4);

#define DECL_SLOT(n) bf16x4 r##n, k##n, a##n, bb##n; f32x4 w##n; unsigned short v##n;
  DECL_SLOT(0) DECL_SLOT(1) DECL_SLOT(2) DECL_SLOT(3)

#define ISSUE(n, t)                                              \
  {                                                              \
    int ti = (t) < T_ ? (t) : T_ - 1;                            \
    size_t eo = base + (size_t)ti * C_;                          \
    size_t ee = eo + e4;                                         \
    r##n = *(const bf16x4*)(RB + ee);                            \
    k##n = *(const bf16x4*)(KB + ee);                            \
    a##n = *(const bf16x4*)(AHB + ee);                           \
    bb##n = *(const bf16x4*)(BHB + ee);                          \
    w##n = *(const f32x4*)(WD + ee);                             \
    v##n = VB[eo + row];                                         \
  }

#define STEP(n, t)                                               \
  {                                                              \
    float rr[4], kk[4], aa[4], bv[4];                            \
    _Pragma("unroll") for (int j = 0; j < 4; ++j) {              \
      rr[j] = (float)r##n[j];                                    \
      kk[j] = (float)k##n[j];                                    \
      aa[j] = (float)a##n[j];                                    \
      bv[j] = (float)bb##n[j];                                   \
    }                                                            \
    float sa = S[0] * aa[0];                                     \
    sa = fmaf(S[1], aa[1], sa);                                  \
    sa = fmaf(S[2], aa[2], sa);                                  \
    sa = fmaf(S[3], aa[3], sa);                                  \
    sa = rsum16(sa);                                             \
    float vi = bf2f(v##n);                                       \
    float o = 0.f;                                               \
    _Pragma("unroll") for (int j = 0; j < 4; ++j) {              \
      S[j] = fmaf(S[j], w##n[j], fmaf(sa, bv[j], vi * kk[j]));   \
      o = fmaf(S[j], rr[j], o);                                  \
    }                                                            \
    o = rsum16(o);                                               \
    if (e == 0) out[base + (size_t)(t) * C_ + row] = o;          \
  }

  ISSUE(0, 0) ISSUE(1, 1) ISSUE(2, 2)
#pragma unroll 1
  for (int t = 0; t < T_; t += 4) {
    ISSUE(3, t + 3) STEP(0, t)
    ISSUE(0, t + 4) STEP(1, t + 1)
    ISSUE(1, t + 5) STEP(2, t + 2)
    ISSUE(2, t + 6) STEP(3, t + 3)
  }
#undef DECL_SLOT
#undef ISSUE
#undef STEP
}

// ---------------- GroupNorm + bonus + gate (wave per (b,t,h)) ----------------
__global__ __launch_bounds__(256) void k_gn(
    const float* __restrict__ o, const unsigned short* __restrict__ rb,
    const unsigned short* __restrict__ kb, const unsigned short* __restrict__ v,
    const unsigned short* __restrict__ g, const float* __restrict__ r_k,
    const float* __restrict__ lnw, const float* __restrict__ lnb,
    unsigned short* __restrict__ outg) {
  int wid = blockIdx.x * 4 + (threadIdx.x >> 6);
  int lane = threadIdx.x & 63;
  int h = wid & (H_ - 1);
  size_t bt = (size_t)(wid >> 5);
  size_t off = bt * C_ + h * 64 + lane;
  int c = h * 64 + lane;
  float x = o[off];
  float mu = x;
#pragma unroll
  for (int m = 1; m < 64; m <<= 1) mu += __shfl_xor(mu, m);
  mu *= (1.f / 64.f);
  float d = x - mu;
  float var = d * d;
#pragma unroll
  for (int m = 1; m < 64; m <<= 1) var += __shfl_xor(var, m);
  var *= (1.f / 64.f);
  float y = d * rsqrtf(var + 6.4e-4f) * lnw[c] + lnb[c];
  float bd = bf2f(rb[off]) * bf2f(kb[off]) * r_k[c];
#pragma unroll
  for (int m = 1; m < 64; m <<= 1) bd += __shfl_xor(bd, m);
  float res = (y + bd * bf2f(v[off])) * bf2f(g[off]);
  outg[off] = f2bf(res);
}

// ---------------- host launch ----------------
extern "C" void kernel_launch(void* const* d_in, const int* in_sizes, int n_in,
                              void* d_out, int out_size, void* d_ws, size_t ws_size,
                              hipStream_t stream) {
  const float* x      = (const float*)d_in[0];
  const float* vfirst = (const float*)d_in[1];
  const float* xprev  = (const float*)d_in[2];
  const float* wkv0   = (const float*)d_in[3];
  const float* x_r = (const float*)d_in[4];
  const float* x_w = (const float*)d_in[5];
  const float* x_k = (const float*)d_in[6];
  const float* x_v = (const float*)d_in[7];
  const float* x_a = (const float*)d_in[8];
  const float* x_g = (const float*)d_in[9];
  const float* w0 = (const float*)d_in[10];
  const float* w1 = (const float*)d_in[11];
  const float* w2 = (const float*)d_in[12];
  const float* a0 = (const float*)d_in[13];
  const float* a1 = (const float*)d_in[14];
  const float* a2 = (const float*)d_in[15];
  const float* v0 = (const float*)d_in[16];
  const float* v1 = (const float*)d_in[17];
  const float* v2 = (const float*)d_in[18];
  const float* g1 = (const float*)d_in[19];
  const float* g2 = (const float*)d_in[20];
  const float* k_k = (const float*)d_in[21];
  const float* k_a = (const float*)d_in[22];
  const float* r_k = (const float*)d_in[23];
  const float* Wr = (const float*)d_in[24];
  const float* Wk = (const float*)d_in[25];
  const float* Wv = (const float*)d_in[26];
  const float* Wo = (const float*)d_in[27];
  const float* lnw = (const float*)d_in[28];
  const float* lnb = (const float*)d_in[29];
  float* out = (float*)d_out;
  char* ws = (char*)d_ws;

  // ---- workspace layout (~239 MiB, unchanged from passing round) ----
  size_t woff = 0;
  auto alloc = [&](size_t n) { char* p = ws + woff; woff += n; return p; };
  char* R1 = alloc(67108864);                       // ABF|SVB -> WD (f32)
  unsigned short* ABF = (unsigned short*)R1;
  unsigned short* SVB = (unsigned short*)(R1 + 33554432);
  float* WD = (float*)R1;
  unsigned short* WT  = (unsigned short*)alloc(8388608);   // transposed big weight
  unsigned short* W1T = (unsigned short*)alloc(262144);
  unsigned short* A1T = (unsigned short*)alloc(262144);
  unsigned short* V1T = (unsigned short*)alloc(131072);
  unsigned short* G1T = (unsigned short*)alloc(524288);
  unsigned short* W2T = (unsigned short*)alloc(262144);
  unsigned short* A2T = (unsigned short*)alloc(262144);
  unsigned short* V2T = (unsigned short*)alloc(131072);
  unsigned short* G2T = (unsigned short*)alloc(524288);
  unsigned short* HWB = (unsigned short*)alloc(1048576);
  unsigned short* HAB = (unsigned short*)alloc(1048576);
  unsigned short* HVB = (unsigned short*)alloc(524288);
  unsigned short* HGB = (unsigned short*)alloc(2097152);
  unsigned short* RB  = (unsigned short*)alloc(33554432);
  unsigned short* KB  = (unsigned short*)alloc(33554432);
  unsigned short* VB  = (unsigned short*)alloc(33554432);
  unsigned short* AHB = (unsigned short*)alloc(33554432);
  unsigned short* BHB = (unsigned short*)alloc(33554432);
  // Temporal overlays (regions dead at the time of each use):
  unsigned short* XMr = VB;   // x_r mix: dead once V-GEMM writes VB
  unsigned short* XMv = KB;   // x_v mix: dead once K-GEMM writes KB
  unsigned short* XMk = SVB;  // x_k mix: SVB dead after V-GEMM; WD overlays later
  unsigned short* GBF  = AHB; // post-scan overlay (AHB dead)
  unsigned short* OUTG = BHB; // post-scan overlay (BHB dead)

  dim3 blk(256);
  dim3 gg(16, 64);

  // small weight transposes (K-contiguous layouts)
  k_transpose<<<dim3(2, 64), blk, 0, stream>>>(w1, W1T, 2048, 64);
  k_transpose<<<dim3(2, 64), blk, 0, stream>>>(a1, A1T, 2048, 64);
  k_transpose<<<dim3(1, 64), blk, 0, stream>>>(v1, V1T, 2048, 32);
  k_transpose<<<dim3(4, 64), blk, 0, stream>>>(g1, G1T, 2048, 128);
  k_transpose<<<dim3(64, 2), blk, 0, stream>>>(w2, W2T, 64, 2048);
  k_transpose<<<dim3(64, 2), blk, 0, stream>>>(a2, A2T, 64, 2048);
  k_transpose<<<dim3(64, 1), blk, 0, stream>>>(v2, V2T, 32, 2048);
  k_transpose<<<dim3(64, 4), blk, 0, stream>>>(g2, G2T, 128, 2048);

  // mix prep for r and v (x read once, two bf16 mixes out)
  k_prep2<<<dim3(M_), blk, 0, stream>>>(x, xprev, x_r, x_v, XMr, XMv);

  // a-chain (fused mix), v-chain (plain XMv)
  k_down<64, 0, true><<<dim3(64), blk, 0, stream>>>(nullptr, x, xprev, x_a, A1T, HAB);
  k_up<64, 1><<<gg, blk, 0, stream>>>(HAB, A2T, a0, nullptr, ABF);
  k_down<32, 0, false><<<dim3(64), blk, 0, stream>>>(XMv, nullptr, nullptr, nullptr, V1T, HVB);
  k_up<32, 1><<<gg, blk, 0, stream>>>(HVB, V2T, v0, nullptr, SVB);

  // R projection (XMr in VB region; VB written only later by V-GEMM)
  k_transpose<<<dim3(64, 64), blk, 0, stream>>>(Wr, WT, 2048, 2048);
  k_gemm_big<0><<<gg, blk, 0, stream>>>(XMr, WT,
      nullptr, RB, nullptr, nullptr, nullptr, nullptr, nullptr, nullptr, nullptr);

  // V projection (reads XMv from KB region + SVB; writes VB, killing XMr)
  k_transpose<<<dim3(64, 64), blk, 0, stream>>>(Wv, WT, 2048, 2048);
  k_gemm_big<1><<<gg, blk, 0, stream>>>(XMv, WT,
      nullptr, VB, SVB, vfirst, nullptr, nullptr, nullptr, nullptr, nullptr);

  // K projection (XMk overlays dead SVB; writes KB killing XMv, + AHB/BHB)
  k_prep1<<<dim3(M_), blk, 0, stream>>>(x, xprev, x_k, XMk);
  k_transpose<<<dim3(64, 64), blk, 0, stream>>>(Wk, WT, 2048, 2048);
  k_gemm_big<2><<<gg, blk, 0, stream>>>(XMk, WT,
      nullptr, KB, nullptr, nullptr, ABF, k_k, k_a, AHB, BHB);

  // w-chain (fused mix; WD overlays ABF + XMk, both dead now)
  k_down<64, 1, true><<<dim3(64), blk, 0, stream>>>(nullptr, x, xprev, x_w, W1T, HWB);
  k_up<64, 0><<<gg, blk, 0, stream>>>(HWB, W2T, w0, WD, nullptr);

  // recurrent scan (register-only; 2048 one-wave blocks)
  k_scan<<<dim3(2048), dim3(64), 0, stream>>>(RB, WD, KB, VB, AHB, BHB, wkv0, out);

  // g-chain (post-scan; GBF overlays AHB)
  k_down<128, 2, true><<<dim3(64), blk, 0, stream>>>(nullptr, x, xprev, x_g, G1T, HGB);
  k_up<128, 3><<<gg, blk, 0, stream>>>(HGB, G2T, nullptr, nullptr, GBF);

  // GroupNorm + bonus + gate (OUTG overlays BHB)
  k_gn<<<dim3(65536), blk, 0, stream>>>(out, RB, KB, VB, GBF, r_k, lnw, lnb, OUTG);

  // final projection
  k_transpose<<<dim3(64, 64), blk, 0, stream>>>(Wo, WT, 2048, 2048);
  k_gemm_big<3><<<gg, blk, 0, stream>>>(OUTG, WT,
      out, nullptr, nullptr, nullptr, nullptr, nullptr, nullptr, nullptr, nullptr);
}